// Round 1
// baseline (408.986 us; speedup 1.0000x reference)
//
#include <hip/hip_runtime.h>
#include <hip/hip_fp16.h>

#define TILE 16

// Fused ModernNet forward, fp32 math, f16 LDS storage.
// One block = 16 samples. Stages: load -> conv1 -> conv2(grouped) -> fc1 -> fc2.
__global__ __launch_bounds__(256, 2) void modernnet_fwd(
    const float* __restrict__ x,
    const float* __restrict__ H1w, const float* __restrict__ H1b,
    const float* __restrict__ H2w, const float* __restrict__ H2b,
    const float* __restrict__ H3w, const float* __restrict__ H3b,
    const float* __restrict__ outw, const float* __restrict__ outb,
    float* __restrict__ out)
{
    // padded conv1 input (20x20, border = -1)
    __shared__ __half xs[TILE][20][20];
    // conv1 output, unpadded 12ch x 8x8; flat per-sample with +8 half pad to
    // break the 384-dword (bank-aligned) sample stride
    __shared__ __half h1[TILE][12 * 64 + 8];
    __shared__ __half h2[TILE][192];      // conv2 output, NCHW-flat (oc*16+oh*4+ow)
    __shared__ __half h3[TILE][32];       // fc1 output (30 used)
    __shared__ __half w1L[25][12];        // [kh*5+kw][oc]
    __shared__ __half b1L[768];           // [oc*64 + oh*8 + ow]
    __shared__ __half w2L[8][5][5][12];   // [icl][kh][kw][oc]
    __shared__ __half b2L[192];           // [oc*16 + oh*4 + ow]
    __shared__ __half w3L[192][30];       // [k][j]
    __shared__ float  b3L[30];
    __shared__ __half w4L[300];           // [k*10 + j]
    __shared__ float  b4L[10];

    const int t = threadIdx.x;
    const int sbase = blockIdx.x * TILE;
    const int s  = t >> 4;    // sample within tile
    const int sl = t & 15;    // slot

    // ---------- stage A1: memset xs to -1.0h, stage all weights ----------
    {
        unsigned int* p = (unsigned int*)&xs[0][0][0];
        for (int i = t; i < TILE * 20 * 20 / 2; i += 256) p[i] = 0xBC00BC00u;
    }
    for (int i = t; i < 300; i += 256) {
        int oc = i / 25, tap = i % 25;
        w1L[tap][oc] = __float2half(H1w[i]);
    }
    for (int i = t; i < 768; i += 256) b1L[i] = __float2half(H1b[i]);
    for (int i = t; i < 2400; i += 256) {
        int oc = i / 200, rem = i % 200, icl = rem / 25, tap = rem % 25;
        w2L[icl][tap / 5][tap % 5][oc] = __float2half(H2w[i]);
    }
    for (int i = t; i < 192; i += 256) b2L[i] = __float2half(H2b[i]);
    for (int i = t; i < 5760; i += 256) ((__half*)w3L)[i] = __float2half(H3w[i]);
    for (int i = t; i < 30; i += 256) b3L[i] = H3b[i];
    for (int i = t; i < 300; i += 256) w4L[i] = __float2half(outw[i]);
    for (int i = t; i < 10; i += 256) b4L[i] = outb[i];
    __syncthreads();

    // ---------- stage A2: load x interior (16x16 per sample) ----------
    {
        const float* xblk = x + (size_t)sbase * 256;
        #pragma unroll
        for (int k = 0; k < 4; ++k) {
            int flat = k * 1024 + t * 4;     // 4096 floats per tile
            float4 v = *(const float4*)(xblk + flat);
            int ls = flat >> 8, pos = flat & 255, r = pos >> 4, c = pos & 15;
            *(__half2*)&xs[ls][r + 2][c + 2] = __floats2half2_rn(v.x, v.y);
            *(__half2*)&xs[ls][r + 2][c + 4] = __floats2half2_rn(v.z, v.w);
        }
    }
    __syncthreads();

    // ---------- stage B: conv1  (slot -> oh = sl>>1, oc-half = sl&1) ----------
    {
        const int oh = sl >> 1;
        const int hb = (sl & 1) * 6;
        float acc[6][8];
        #pragma unroll
        for (int j = 0; j < 6; ++j)
            #pragma unroll
            for (int ow = 0; ow < 8; ++ow) acc[j][ow] = 0.f;

        for (int kh = 0; kh < 5; ++kh) {
            const int r = 2 * oh + kh;           // padded row 0..18
            float xv[20];
            const __half2* rp = (const __half2*)&xs[s][r][0];
            #pragma unroll
            for (int k = 0; k < 10; ++k) {
                float2 f = __half22float2(rp[k]);
                xv[2 * k] = f.x; xv[2 * k + 1] = f.y;
            }
            #pragma unroll
            for (int kw = 0; kw < 5; ++kw) {
                float wv[6];
                #pragma unroll
                for (int j = 0; j < 6; ++j) wv[j] = __half2float(w1L[kh * 5 + kw][hb + j]);
                #pragma unroll
                for (int ow = 0; ow < 8; ++ow) {
                    float v = xv[2 * ow + kw];
                    #pragma unroll
                    for (int j = 0; j < 6; ++j) acc[j][ow] = fmaf(v, wv[j], acc[j][ow]);
                }
            }
        }
        #pragma unroll
        for (int j = 0; j < 6; ++j) {
            const int oc = hb + j;
            #pragma unroll
            for (int ow = 0; ow < 8; ow += 2) {
                float v0 = fmaxf(acc[j][ow]     + __half2float(b1L[oc * 64 + oh * 8 + ow]),     0.f);
                float v1 = fmaxf(acc[j][ow + 1] + __half2float(b1L[oc * 64 + oh * 8 + ow + 1]), 0.f);
                *(__half2*)&h1[s][(oc * 8 + oh) * 8 + ow] = __floats2half2_rn(v0, v1);
            }
        }
    }
    __syncthreads();

    // ---------- stage C: conv2 grouped (slot -> oh = sl>>2, group q = sl&3; q==3 idle) ----------
    {
        const int oh = sl >> 2;
        const int q  = sl & 3;
        if (q < 3) {
            float acc[4][4];
            #pragma unroll
            for (int j = 0; j < 4; ++j)
                #pragma unroll
                for (int ow = 0; ow < 4; ++ow) acc[j][ow] = 0.f;

            for (int icl = 0; icl < 8; ++icl) {
                // channel-slice map: q0: 0..7, q1: 4..11, q2: {0..3, 8..11}
                const int ic = (q == 0) ? icl : (q == 1) ? icl + 4 : (icl < 4 ? icl : icl + 4);
                #pragma unroll
                for (int kh = 0; kh < 5; ++kh) {
                    const int r = 2 * oh + kh - 2;    // h1 row, -2..9
                    float xv[12];                      // padded cols -2..9
                    if (r >= 0 && r < 8) {
                        const __half2* rp = (const __half2*)&h1[s][(ic * 8 + r) * 8];
                        #pragma unroll
                        for (int k = 0; k < 4; ++k) {
                            float2 f = __half22float2(rp[k]);
                            xv[2 + 2 * k] = f.x; xv[3 + 2 * k] = f.y;
                        }
                    } else {
                        #pragma unroll
                        for (int k = 0; k < 8; ++k) xv[2 + k] = -1.0f;
                    }
                    xv[0] = xv[1] = xv[10] = xv[11] = -1.0f;
                    #pragma unroll
                    for (int kw = 0; kw < 5; ++kw) {
                        float wv[4];
                        #pragma unroll
                        for (int j = 0; j < 4; ++j) wv[j] = __half2float(w2L[icl][kh][kw][q * 4 + j]);
                        #pragma unroll
                        for (int ow = 0; ow < 4; ++ow) {
                            float v = xv[2 * ow + kw];
                            #pragma unroll
                            for (int j = 0; j < 4; ++j) acc[j][ow] = fmaf(v, wv[j], acc[j][ow]);
                        }
                    }
                }
            }
            #pragma unroll
            for (int j = 0; j < 4; ++j) {
                const int oc = q * 4 + j;
                #pragma unroll
                for (int ow = 0; ow < 4; ow += 2) {
                    float v0 = fmaxf(acc[j][ow]     + __half2float(b2L[oc * 16 + oh * 4 + ow]),     0.f);
                    float v1 = fmaxf(acc[j][ow + 1] + __half2float(b2L[oc * 16 + oh * 4 + ow + 1]), 0.f);
                    *(__half2*)&h2[s][oc * 16 + oh * 4 + ow] = __floats2half2_rn(v0, v1);
                }
            }
        }
    }
    __syncthreads();

    // ---------- stage D: fc1 (slot < 15 -> outputs j and j+15) ----------
    if (sl < 15) {
        const int j0 = sl, j1 = sl + 15;
        float a0 = 0.f, a1 = 0.f;
        const __half2* hp = (const __half2*)&h2[s][0];
        for (int k2 = 0; k2 < 96; ++k2) {
            float2 f = __half22float2(hp[k2]);
            const int k = 2 * k2;
            a0 = fmaf(f.x, __half2float(w3L[k][j0]),     a0);
            a0 = fmaf(f.y, __half2float(w3L[k + 1][j0]), a0);
            a1 = fmaf(f.x, __half2float(w3L[k][j1]),     a1);
            a1 = fmaf(f.y, __half2float(w3L[k + 1][j1]), a1);
        }
        h3[s][j0] = __float2half(fmaxf(a0 + b3L[j0], 0.f));
        h3[s][j1] = __float2half(fmaxf(a1 + b3L[j1], 0.f));
    }
    __syncthreads();

    // ---------- stage E: fc2 (slot < 10 -> one logit) ----------
    if (sl < 10) {
        float a = b4L[sl];
        #pragma unroll
        for (int k = 0; k < 30; ++k)
            a = fmaf(__half2float(h3[s][k]), __half2float(w4L[k * 10 + sl]), a);
        out[(size_t)(sbase + s) * 10 + sl] = a;
    }
}

extern "C" void kernel_launch(void* const* d_in, const int* in_sizes, int n_in,
                              void* d_out, int out_size, void* d_ws, size_t ws_size,
                              hipStream_t stream) {
    const float* x    = (const float*)d_in[0];
    const float* H1w  = (const float*)d_in[1];
    const float* H1b  = (const float*)d_in[2];
    const float* H2w  = (const float*)d_in[3];
    const float* H2b  = (const float*)d_in[4];
    const float* H3w  = (const float*)d_in[5];
    const float* H3b  = (const float*)d_in[6];
    const float* outw = (const float*)d_in[7];
    const float* outb = (const float*)d_in[8];
    float* outp = (float*)d_out;

    const int B = in_sizes[0] / 256;      // 131072
    const int blocks = B / TILE;          // 8192
    modernnet_fwd<<<blocks, 256, 0, stream>>>(x, H1w, H1b, H2w, H2b,
                                              H3w, H3b, outw, outb, outp);
}

// Round 2
// 160.173 us; speedup vs baseline: 2.5534x; 2.5534x over previous
//
#include <hip/hip_runtime.h>
#include <hip/hip_fp16.h>

typedef _Float16 f16x8 __attribute__((ext_vector_type(8)));
typedef float f32x4 __attribute__((ext_vector_type(4)));

union U4H8 { uint4 u; f16x8 h; };
__device__ inline f16x8 asH(uint4 u){ U4H8 x; x.u = u; return x.h; }
__device__ inline unsigned int pk(float a, float b){
    __half2 h = __floats2half2_rn(a, b);
    union { __half2 h; unsigned int u; } c; c.h = h; return c.u;
}

// ws layout (dword indices): frags uint4[30][64] = dwords [0,7680);
// bias1 f32[4][4][64] at 7680; bias2 f32[4][64] at 8704; end 8960 dwords.
#define WS_B1 7680
#define WS_B2 8704

// ---------------- setup kernel: build per-lane MFMA B-fragments ----------------
// frag index fi: 0-1 conv1 (K=64), 2-16 conv2 (K=480), 17-28 fc1 (nt*6+kk), 29 fc2
__global__ __launch_bounds__(256) void build_tables(
    const float* __restrict__ H1w, const float* __restrict__ H1b,
    const float* __restrict__ H2w, const float* __restrict__ H2b,
    const float* __restrict__ H3w, const float* __restrict__ outw,
    unsigned int* __restrict__ ws)
{
    const int t = threadIdx.x, lane = t & 63, wv = t >> 6;
    const int ch = lane >> 4, oc = lane & 15;

    for (int fi = wv; fi < 30; fi += 4) {
        unsigned short us[8];
        for (int j = 0; j < 8; ++j) {
            float w = 0.f;
            if (fi < 2) {                       // conv1: k = kh*8 + c
                int g = fi*4 + ch;              // kh
                if (g < 5 && j < 5 && oc < 12) w = H1w[oc*25 + g*5 + j];
            } else if (fi < 17) {               // conv2: k = (ic*5+kh)*8 + c
                int g = (fi-2)*4 + ch;          // 0..59
                int ic = g/5, kh = g - ic*5;
                if (j < 5 && oc < 12) {
                    int q = oc >> 2, ok, icl;
                    if (q == 0)      { ok = (ic < 8);                icl = ic;            }
                    else if (q == 1) { ok = (ic >= 4);               icl = ic - 4;        }
                    else             { ok = (ic < 4) || (ic >= 8);   icl = ic < 4 ? ic : ic - 4; }
                    if (ok) w = H2w[((oc*8 + icl)*5 + kh)*5 + j];
                }
            } else if (fi < 29) {               // fc1
                int idx = fi - 17, nt = idx/6, kk = idx - nt*6;
                int k = kk*32 + ch*8 + j, col = nt*16 + oc;
                if (col < 30) w = H3w[k*30 + col];
            } else {                            // fc2
                int k = ch*8 + j;
                if (k < 30 && oc < 10) w = outw[k*10 + oc];
            }
            __half hh = __float2half(w);
            union { __half h; unsigned short s; } cv; cv.h = hh; us[j] = cv.s;
        }
        uint4 u;
        u.x = us[0] | ((unsigned int)us[1] << 16);
        u.y = us[2] | ((unsigned int)us[3] << 16);
        u.z = us[4] | ((unsigned int)us[5] << 16);
        u.w = us[6] | ((unsigned int)us[7] << 16);
        ((uint4*)ws)[fi*64 + lane] = u;
    }

    float* wsf = (float*)ws;
    if (wv == 1) {          // conv1 bias C-frags, 4 tile-parities
        for (int t4 = 0; t4 < 4; ++t4)
            for (int r = 0; r < 4; ++r) {
                int pos = ch*4 + r, oh = 2*t4 + (pos >> 3), ow = pos & 7;
                wsf[WS_B1 + (t4*4 + r)*64 + lane] = (oc < 12) ? H1b[oc*64 + oh*8 + ow] : 0.f;
            }
    }
    if (wv == 2) {          // conv2 bias C-frag
        for (int r = 0; r < 4; ++r) {
            int pos = ch*4 + r;
            wsf[WS_B2 + r*64 + lane] = (oc < 12) ? H2b[oc*16 + pos] : 0.f;
        }
    }
}

// ---------------- main kernel: 8 samples / block, 4 waves ----------------
// LDS bytes: xs [8][20][24]h @0 (7680) | h1p [8][12][12][18]h @7680 (41472)
//            h2 [8][192]h @49152 (3072) | h3 [8][32]h @52224 (512)  -> 52736 B
__global__ __launch_bounds__(256, 3) void modernnet_mfma(
    const float* __restrict__ x, const unsigned int* __restrict__ ws,
    const float* __restrict__ H3b, const float* __restrict__ outb,
    float* __restrict__ out)
{
    __shared__ unsigned int lds[13184];
    const int t = threadIdx.x, wave = t >> 6, l = t & 63;
    const int ch = l >> 4, oc = l & 15;
    const int sbase = blockIdx.x * 8;

    // preload B-frags / bias-frags (registers, per wave)
    const uint4* fr = (const uint4*)ws;
    uint4 c1b0 = fr[0*64 + l], c1b1 = fr[1*64 + l];
    uint4 c2b[15];
    #pragma unroll
    for (int kk = 0; kk < 15; ++kk) c2b[kk] = fr[(2 + kk)*64 + l];
    const float* wsf = (const float*)ws;
    f32x4 b1f[4];
    #pragma unroll
    for (int t4 = 0; t4 < 4; ++t4) {
        #pragma unroll
        for (int r = 0; r < 4; ++r) b1f[t4][r] = wsf[WS_B1 + (t4*4 + r)*64 + l];
    }
    f32x4 b2f;
    #pragma unroll
    for (int r = 0; r < 4; ++r) b2f[r] = wsf[WS_B2 + r*64 + l];

    // conv2 per-lane (ic,kh) byte offsets within a sample's h1p image
    int c2off[15];
    #pragma unroll
    for (int kk = 0; kk < 15; ++kk) {
        int g = kk*4 + ch, ic = g/5, kh = g - ic*5;
        c2off[kk] = ic*432 + kh*36;
    }

    // phase 0: memset xs+h1p to half(-1), h3 to 0
    for (int i = t; i < 12288; i += 256) lds[i] = 0xBC00BC00u;
    if (t < 128) lds[13056 + t] = 0u;
    __syncthreads();

    // phase 1: xs interior [2..17][2..17]
    {
        const float* xp = x + (size_t)sbase*256 + t*8;
        float4 v0 = *(const float4*)xp;
        float4 v1 = *(const float4*)(xp + 4);
        int s = t >> 5, pos = (t*8) & 255, r = pos >> 4, c = pos & 15;
        int d = (s*960 + (2 + r)*48 + (2 + c)*2) >> 2;
        lds[d]     = pk(v0.x, v0.y); lds[d + 1] = pk(v0.z, v0.w);
        lds[d + 2] = pk(v1.x, v1.y); lds[d + 3] = pk(v1.z, v1.w);
    }
    __syncthreads();

    // phase 2: conv1 — 32 M-tiles (sample s, oh-pair tt), 8 per wave, 2 MFMA each
    #pragma unroll
    for (int ti = 0; ti < 8; ++ti) {
        const int tile = wave*8 + ti, s = tile >> 2, tt = tile & 3;
        const int ohA = 2*tt + (oc >> 3), owA = oc & 7;       // A-row = l&15
        const int base = s*960 + ohA*96 + owA*4;              // bytes
        const int d0 = (base + ch*48) >> 2;
        uint4 a0 = make_uint4(lds[d0], lds[d0+1], lds[d0+2], lds[d0+3]);
        uint4 a1 = make_uint4(0u, 0u, 0u, 0u);
        if (ch == 0) {
            const int d1 = (base + 192) >> 2;                 // kh = 4 row
            a1 = make_uint4(lds[d1], lds[d1+1], lds[d1+2], lds[d1+3]);
        }
        f32x4 acc = b1f[tt];
        acc = __builtin_amdgcn_mfma_f32_16x16x32_f16(asH(a0), asH(c1b0), acc, 0, 0, 0);
        acc = __builtin_amdgcn_mfma_f32_16x16x32_f16(asH(a1), asH(c1b1), acc, 0, 0, 0);
        if (oc < 12) {                                        // C: col=oc, row=4*ch+r
            const int ohC = 2*tt + (ch >> 1), ow0 = 4*(ch & 1);
            const int d = 1920 + s*1296 + oc*108 + (ohC + 2)*9 + 1 + (ch & 1)*2;
            lds[d]     = pk(fmaxf(acc[0], 0.f), fmaxf(acc[1], 0.f));
            lds[d + 1] = pk(fmaxf(acc[2], 0.f), fmaxf(acc[3], 0.f));
            (void)ow0;
        }
    }
    __syncthreads();

    // phase 3: conv2 — 8 M-tiles (1 sample each), 2 per wave, 15 MFMA each
    #pragma unroll
    for (int i = 0; i < 2; ++i) {
        const int s = wave*2 + i;
        const int ohA = oc >> 2, owA = oc & 3;
        const int abase = 7680 + s*5184 + ohA*72 + owA*4;     // bytes
        f32x4 acc = b2f;
        #pragma unroll
        for (int kk = 0; kk < 15; ++kk) {
            const int d = (abase + c2off[kk]) >> 2;
            uint4 a = make_uint4(lds[d], lds[d+1], lds[d+2], lds[d+3]);
            acc = __builtin_amdgcn_mfma_f32_16x16x32_f16(asH(a), asH(c2b[kk]), acc, 0, 0, 0);
        }
        if (oc < 12) {                                        // h2[s][oc*16 + 4*ch + r]
            const int d = (49152 + s*384 + oc*32 + ch*8) >> 2;
            lds[d]     = pk(fmaxf(acc[0], 0.f), fmaxf(acc[1], 0.f));
            lds[d + 1] = pk(fmaxf(acc[2], 0.f), fmaxf(acc[3], 0.f));
        }
    }
    __syncthreads();

    // phase 4: fc1 — waves 0,1 (N-tile = wave), K=192 (6 steps)
    if (wave < 2) {
        const int nt = wave, sm = oc & 7, coln = nt*16 + oc;
        const float bias = (coln < 30) ? H3b[coln] : 0.f;
        f32x4 acc = { bias, bias, bias, bias };
        #pragma unroll
        for (int kk = 0; kk < 6; ++kk) {
            const int d = (49152 + sm*384 + kk*64 + ch*16) >> 2;
            uint4 a = make_uint4(lds[d], lds[d+1], lds[d+2], lds[d+3]);
            uint4 b = fr[(17 + nt*6 + kk)*64 + l];
            acc = __builtin_amdgcn_mfma_f32_16x16x32_f16(asH(a), asH(b), acc, 0, 0, 0);
        }
        #pragma unroll
        for (int r = 0; r < 4; ++r) {
            const int mrow = ch*4 + r;
            if (mrow < 8 && coln < 30) {
                __half hv = __float2half(fmaxf(acc[r], 0.f));
                union { __half h; unsigned short s; } cv; cv.h = hv;
                ((unsigned short*)lds)[26112 + mrow*32 + coln] = cv.s;
            }
        }
    }
    __syncthreads();

    // phase 5: fc2 — wave 0, K=30(->32), 1 MFMA
    if (wave == 0) {
        const int sm = oc & 7;
        const int d = (52224 + sm*64 + ch*16) >> 2;
        uint4 a = make_uint4(lds[d], lds[d+1], lds[d+2], lds[d+3]);
        uint4 b = fr[29*64 + l];
        const float bias = (oc < 10) ? outb[oc] : 0.f;
        f32x4 acc = { bias, bias, bias, bias };
        acc = __builtin_amdgcn_mfma_f32_16x16x32_f16(asH(a), asH(b), acc, 0, 0, 0);
        #pragma unroll
        for (int r = 0; r < 4; ++r) {
            const int mrow = ch*4 + r;
            if (mrow < 8 && oc < 10)
                out[(size_t)(sbase + mrow)*10 + oc] = acc[r];
        }
    }
}

extern "C" void kernel_launch(void* const* d_in, const int* in_sizes, int n_in,
                              void* d_out, int out_size, void* d_ws, size_t ws_size,
                              hipStream_t stream) {
    const float* x    = (const float*)d_in[0];
    const float* H1w  = (const float*)d_in[1];
    const float* H1b  = (const float*)d_in[2];
    const float* H2w  = (const float*)d_in[3];
    const float* H2b  = (const float*)d_in[4];
    const float* H3w  = (const float*)d_in[5];
    const float* H3b  = (const float*)d_in[6];
    const float* outw = (const float*)d_in[7];
    const float* outb = (const float*)d_in[8];
    float* outp = (float*)d_out;
    unsigned int* ws = (unsigned int*)d_ws;

    build_tables<<<1, 256, 0, stream>>>(H1w, H1b, H2w, H2b, H3w, outw, ws);

    const int B = in_sizes[0] / 256;          // 131072
    const int blocks = B / 8;                 // 16384
    modernnet_mfma<<<blocks, 256, 0, stream>>>(x, ws, H3b, outb, outp);
}